// Round 13
// baseline (2358.497 us; speedup 1.0000x reference)
//
#include <hip/hip_runtime.h>
#include <hip/hip_bf16.h>

// GraphSAGE 3-layer. ROUND-13 PROBE on top of Round-12 (best: 255.9 us).
// Idempotent internal rep loops push each suspect kernel over the ~213 us
// harness-fill wall so the top-5 table gives per-unit dur + counters:
//   gemm0 x16, gather1 x24, scanpack x48, fillscatter x40, final x64.
// Plus 64 no-op dispatches to measure per-launch overhead:
//   gap = (dur - 255.9 - sum(probe deltas)) / 63.
// histrank/memset/gemm1 solve by elimination. gather0 known (88.6).

typedef short bf16x8 __attribute__((ext_vector_type(8)));
typedef float f32x4 __attribute__((ext_vector_type(4)));

static __device__ __forceinline__ unsigned short f2bf(float f) {
  unsigned u = __float_as_uint(f);
  unsigned r = u + 0x7FFFu + ((u >> 16) & 1u);  // RNE
  return (unsigned short)(r >> 16);
}
static __device__ __forceinline__ float bf2f_lo(unsigned u) {
  return __uint_as_float(u << 16);
}
static __device__ __forceinline__ float bf2f_hi(unsigned u) {
  return __uint_as_float(u & 0xFFFF0000u);
}
static __device__ __forceinline__ unsigned packbf(float lo, float hi) {
  return ((unsigned)f2bf(hi) << 16) | (unsigned)f2bf(lo);
}

// ---- sizes ----
#define E0C 900000
#define E1C 60000
#define E2C 5120
#define ETC 965120
#define HB  3770

// ---- int-workspace offsets ----
#define ROW0_OFF 0
#define ROW1_OFF 60001
#define ROW2_OFF 66002
#define CNT_OFF  67027
#define RANK_OFF 134051
#define SS0_OFF  1099171
#define SS1_OFF  1999171
#define SS2_OFF  2059171
#define DUMMY_OFF 2064300

struct TileGeom { int tin, goff, n, T; };
static __device__ __forceinline__ TileGeom tile_geom(int b) {
  TileGeom g;
  if (b < 118)      { g.tin = b;       g.goff = 0;     g.n = 60000; g.T = 118; }
  else if (b < 130) { g.tin = b - 118; g.goff = 60000; g.n = 6000;  g.T = 12; }
  else              { g.tin = b - 130; g.goff = 66000; g.n = 1024;  g.T = 2; }
  return g;
}

// ---------- no-op kernel for launch-overhead measurement ----------
__global__ void noop_k(int* __restrict__ p) {
  if (blockIdx.x == 1234567) p[0] = 0;   // never true at grid=1; not DCE-able
}

// ---------- hist with rank capture ----------
__global__ __launch_bounds__(256) void histrank_k(
    const int* __restrict__ d0, const int* __restrict__ d1, const int* __restrict__ d2,
    int* __restrict__ cnt, int* __restrict__ rank) {
  int t = blockIdx.x * 256 + threadIdx.x;
  if (t < E0C) {
    rank[t] = atomicAdd(&cnt[d0[t]], 1);
  } else if (t < E0C + E1C) {
    rank[t] = atomicAdd(&cnt[60000 + d1[t - E0C]], 1);
  } else if (t < ETC) {
    rank[t] = atomicAdd(&cnt[66000 + d2[t - E0C - E1C]], 1);
  }
}

// ---------- per-tile scan + weight packing (rep-able, idempotent) ----------
__global__ __launch_bounds__(256) void scanpack_k(
    const int* __restrict__ cnt,
    int* __restrict__ row0, int* __restrict__ row1, int* __restrict__ row2,
    const float* __restrict__ Wl0, const float* __restrict__ Wr0,
    unsigned short* __restrict__ bm0,
    const float* __restrict__ Wl1, const float* __restrict__ Wr1,
    unsigned short* __restrict__ bm1, int rep) {
  const int b = blockIdx.x;
  const int tid = threadIdx.x;
#pragma unroll 1
  for (int it = 0; it < rep; ++it) {
    if (b < 132) {
      __shared__ int sc[256];
      __syncthreads();
      const TileGeom g = tile_geom(b);
      int* row = (b < 118) ? row0 : (b < 130 ? row1 : row2);
      int p = 0;
      const int lim = g.tin * 512;
      for (int i = tid; i < lim; i += 256) p += cnt[g.goff + i];
      sc[tid] = p;
      __syncthreads();
      for (int off = 128; off; off >>= 1) {
        if (tid < off) sc[tid] += sc[tid + off];
        __syncthreads();
      }
      const int pref = sc[0];
      __syncthreads();
      const int i0 = g.tin * 512 + 2 * tid;
      const int e0 = (i0 < g.n) ? cnt[g.goff + i0] : 0;
      const int e1 = (i0 + 1 < g.n) ? cnt[g.goff + i0 + 1] : 0;
      sc[tid] = e0 + e1;
      __syncthreads();
      for (int off = 1; off < 256; off <<= 1) {
        int v = (tid >= off) ? sc[tid - off] : 0;
        __syncthreads();
        sc[tid] += v;
        __syncthreads();
      }
      const int excl = sc[tid] - (e0 + e1);
      const int o0 = pref + excl;
      const int o1 = o0 + e0;
      if (i0 < g.n) row[i0] = o0;
      if (i0 + 1 < g.n) row[i0 + 1] = o1;
      if (g.tin == g.T - 1 && tid == 255) row[g.n] = pref + sc[255];
    } else {
      int j = b - 132;
      int n = tid;
      if (j < 224) {
        int k = j;
        float v = 0.f;
        if (k < 100) v = Wl0[(size_t)k * 256 + n];
        else if (k >= 112 && k < 212) v = Wr0[(size_t)(k - 112) * 256 + n];
        bm0[(((size_t)(k >> 3) * 256) + n) * 8 + (k & 7)] = f2bf(v);
      } else {
        int k = j - 224;
        float v = (k < 256) ? Wl1[(size_t)k * 256 + n] : Wr1[(size_t)(k - 256) * 256 + n];
        bm1[(((size_t)(k >> 3) * 256) + n) * 8 + (k & 7)] = f2bf(v);
      }
    }
  }
}

// ---------- atomic-free fill (rep-able, idempotent) ----------
__global__ __launch_bounds__(256) void fillscatter_k(
    const int* __restrict__ d0, const int* __restrict__ d1, const int* __restrict__ d2,
    const int* __restrict__ s0, const int* __restrict__ s1, const int* __restrict__ s2,
    const int* __restrict__ row0, const int* __restrict__ row1,
    const int* __restrict__ row2, const int* __restrict__ rank,
    int* __restrict__ o0, int* __restrict__ o1, int* __restrict__ o2, int rep) {
  int t = blockIdx.x * 256 + threadIdx.x;
#pragma unroll 1
  for (int it = 0; it < rep; ++it) {
    if (t < E0C) {
      o0[row0[d0[t]] + rank[t]] = s0[t];
    } else if (t < E0C + E1C) {
      int e = t - E0C;
      o1[row1[d1[e]] + rank[t]] = s1[e];
    } else if (t < ETC) {
      int e = t - E0C - E1C;
      o2[row2[d2[e]] + rank[t]] = s2[e];
    }
  }
}

// ---------- gather0: wave-per-row mean + self-row conversion ----------
__global__ __launch_bounds__(256) void gather_fused_k(
    const float* __restrict__ x, const int* __restrict__ ss,
    const int* __restrict__ rs, unsigned short* __restrict__ am, int n) {
  int idx = blockIdx.x * 256 + threadIdx.x;
  int w = idx >> 6;
  int f = idx & 63;
  if (w >= n) return;
  const int lo = rs[w];
  const int hi = rs[w + 1];
  float acc0 = 0.f, acc1 = 0.f;
  const int k1 = f + 64;
  int e = lo;
  for (; e + 4 <= hi; e += 4) {
    const float* p0 = x + (size_t)ss[e] * 100;
    const float* p1 = x + (size_t)ss[e + 1] * 100;
    const float* p2 = x + (size_t)ss[e + 2] * 100;
    const float* p3 = x + (size_t)ss[e + 3] * 100;
    acc0 += (p0[f] + p1[f]) + (p2[f] + p3[f]);
    if (k1 < 100) acc1 += (p0[k1] + p1[k1]) + (p2[k1] + p3[k1]);
  }
  for (; e < hi; ++e) {
    const float* p0 = x + (size_t)ss[e] * 100;
    acc0 += p0[f];
    if (k1 < 100) acc1 += p0[k1];
  }
  const float inv = 1.f / (float)max(hi - lo, 1);
  unsigned short* arow = am + (size_t)w * 224;
  arow[f] = f2bf(acc0 * inv);
  if (k1 < 112) arow[k1] = (k1 < 100) ? f2bf(acc1 * inv) : (unsigned short)0;
  const float* xrow = x + (size_t)w * 100;
  arow[112 + f] = f2bf(xrow[f]);
  if (k1 < 112) arow[112 + k1] = (k1 < 100) ? f2bf(xrow[k1]) : (unsigned short)0;
}

// ---------- gather1: wave-per-row mean over bf16 h0 rows (rep-able) ----------
__global__ __launch_bounds__(256) void gather_mean_b16_k(
    const unsigned* __restrict__ xbu, const int* __restrict__ ss,
    const int* __restrict__ rs, unsigned* __restrict__ meanu, int n, int rep) {
  int idx = blockIdx.x * 256 + threadIdx.x;
  int w = idx >> 6;
  int f = idx & 63;
  if (w >= n) return;
  const int lo = rs[w];
  const int hi = rs[w + 1];
#pragma unroll 1
  for (int it = 0; it < rep; ++it) {
    float a0l = 0.f, a0h = 0.f, a1l = 0.f, a1h = 0.f;
    int e = lo;
    for (; e + 2 <= hi; e += 2) {
      const unsigned* p0 = xbu + (size_t)ss[e] * 128;
      const unsigned* p1 = xbu + (size_t)ss[e + 1] * 128;
      unsigned u0a = p0[f], u0b = p0[f + 64];
      unsigned u1a = p1[f], u1b = p1[f + 64];
      a0l += bf2f_lo(u0a) + bf2f_lo(u1a);
      a0h += bf2f_hi(u0a) + bf2f_hi(u1a);
      a1l += bf2f_lo(u0b) + bf2f_lo(u1b);
      a1h += bf2f_hi(u0b) + bf2f_hi(u1b);
    }
    for (; e < hi; ++e) {
      const unsigned* p0 = xbu + (size_t)ss[e] * 128;
      unsigned ua = p0[f], ub = p0[f + 64];
      a0l += bf2f_lo(ua); a0h += bf2f_hi(ua);
      a1l += bf2f_lo(ub); a1h += bf2f_hi(ub);
    }
    const float inv = 1.f / (float)max(hi - lo, 1);
    meanu[(size_t)w * 128 + f] = packbf(a0l * inv, a0h * inv);
    meanu[(size_t)w * 128 + f + 64] = packbf(a1l * inv, a1h * inv);
  }
}

// ---------- gemm0 (rep-able): K=224, MBLK=64, LDS-coalesced bf16 epilogue ----------
__global__ __launch_bounds__(256) void gemm0_k(
    const unsigned short* __restrict__ A, const unsigned short* __restrict__ Bp,
    const float* __restrict__ bias, unsigned short* __restrict__ h0b, int M,
    int rep) {
  constexpr int LDA = 232;
  constexpr int LDC = 264;
  __shared__ unsigned short Sh[64 * LDC];

  const int row0 = blockIdx.x * 64;
  const int wid = threadIdx.x >> 6;
  const int l = threadIdx.x & 63;
  const int l15 = l & 15;
  const int lhi = l >> 4;
  const int mrem = M - row0;

#pragma unroll 1
  for (int it = 0; it < rep; ++it) {
    __syncthreads();
    for (int t = threadIdx.x; t < 64 * 28; t += 256) {
      int r = t / 28;
      int c = t - r * 28;
      *reinterpret_cast<uint4*>(&Sh[r * LDA + c * 8]) =
          *reinterpret_cast<const uint4*>(A + (size_t)(row0 + r) * 224 + c * 8);
    }
    __syncthreads();

    f32x4 acc[4][4];
#pragma unroll
    for (int rt = 0; rt < 4; ++rt)
#pragma unroll
      for (int ct = 0; ct < 4; ++ct) acc[rt][ct] = (f32x4){0.f, 0.f, 0.f, 0.f};

    for (int kc = 0; kc < 7; ++kc) {
      bf16x8 a[4], b[4];
#pragma unroll
      for (int rt = 0; rt < 4; ++rt)
        a[rt] = *reinterpret_cast<const bf16x8*>(
            &Sh[(rt * 16 + l15) * LDA + kc * 32 + lhi * 8]);
#pragma unroll
      for (int ct = 0; ct < 4; ++ct) {
        int n = wid * 64 + ct * 16 + l15;
        b[ct] = *reinterpret_cast<const bf16x8*>(
            Bp + ((size_t)(kc * 4 + lhi) * 256 + n) * 8);
      }
#pragma unroll
      for (int rt = 0; rt < 4; ++rt)
#pragma unroll
        for (int ct = 0; ct < 4; ++ct)
          acc[rt][ct] = __builtin_amdgcn_mfma_f32_16x16x32_bf16(a[rt], b[ct],
                                                                acc[rt][ct], 0, 0, 0);
    }
    __syncthreads();

#pragma unroll
    for (int rt = 0; rt < 4; ++rt) {
#pragma unroll
      for (int ct = 0; ct < 4; ++ct) {
        int col = wid * 64 + ct * 16 + l15;
        float bv = bias[col];
#pragma unroll
        for (int r = 0; r < 4; ++r) {
          int rr = rt * 16 + lhi * 4 + r;
          Sh[rr * LDC + col] = f2bf(fmaxf(acc[rt][ct][r] + bv, 0.f));
        }
      }
    }
    __syncthreads();

    for (int t = threadIdx.x; t < 64 * 32; t += 256) {
      int r = t >> 5;
      int c = t & 31;
      if (r < mrem) {
        *reinterpret_cast<uint4*>(h0b + (size_t)(row0 + r) * 256 + c * 8) =
            *reinterpret_cast<const uint4*>(&Sh[r * LDC + c * 8]);
      }
    }
  }
}

// ---------- gemm1: K=512 two-pointer A, f32 out ----------
__global__ __launch_bounds__(256) void gemm1_k(
    const unsigned short* __restrict__ A1, const unsigned short* __restrict__ A2,
    const unsigned short* __restrict__ Bp, const float* __restrict__ bias,
    float* __restrict__ h1, int M) {
  constexpr int LDA = 520;
  __shared__ unsigned short As[32 * LDA];

  const int row0 = blockIdx.x * 32;
  for (int t = threadIdx.x; t < 32 * 64; t += 256) {
    int r = t >> 6;
    int c = t & 63;
    const unsigned short* src = (c < 32)
        ? (A1 + (size_t)(row0 + r) * 256 + c * 8)
        : (A2 + (size_t)(row0 + r) * 256 + (c - 32) * 8);
    *reinterpret_cast<uint4*>(&As[r * LDA + c * 8]) =
        *reinterpret_cast<const uint4*>(src);
  }
  __syncthreads();

  const int wid = threadIdx.x >> 6;
  const int l = threadIdx.x & 63;
  const int l15 = l & 15;
  const int lhi = l >> 4;

  f32x4 acc[2][4];
#pragma unroll
  for (int rt = 0; rt < 2; ++rt)
#pragma unroll
    for (int ct = 0; ct < 4; ++ct) acc[rt][ct] = (f32x4){0.f, 0.f, 0.f, 0.f};

  for (int kc = 0; kc < 16; ++kc) {
    bf16x8 a[2], b[4];
#pragma unroll
    for (int rt = 0; rt < 2; ++rt)
      a[rt] = *reinterpret_cast<const bf16x8*>(
          &As[(rt * 16 + l15) * LDA + kc * 32 + lhi * 8]);
#pragma unroll
    for (int ct = 0; ct < 4; ++ct) {
      int n = wid * 64 + ct * 16 + l15;
      b[ct] = *reinterpret_cast<const bf16x8*>(
          Bp + ((size_t)(kc * 4 + lhi) * 256 + n) * 8);
    }
#pragma unroll
    for (int rt = 0; rt < 2; ++rt)
#pragma unroll
      for (int ct = 0; ct < 4; ++ct)
        acc[rt][ct] = __builtin_amdgcn_mfma_f32_16x16x32_bf16(a[rt], b[ct],
                                                              acc[rt][ct], 0, 0, 0);
  }

#pragma unroll
  for (int rt = 0; rt < 2; ++rt) {
#pragma unroll
    for (int ct = 0; ct < 4; ++ct) {
      int col = wid * 64 + ct * 16 + l15;
      float bv = bias[col];
#pragma unroll
      for (int r = 0; r < 4; ++r) {
        int row = row0 + rt * 16 + lhi * 4 + r;
        if (row < M)
          h1[(size_t)row * 256 + col] = fmaxf(acc[rt][ct][r] + bv, 0.f);
      }
    }
  }
}

// ---------- final (rep-able): 4 waves/block, wave per row ----------
__global__ __launch_bounds__(256) void final_fused_k(
    const float* __restrict__ h1, const int* __restrict__ ss,
    const int* __restrict__ rs, const float* __restrict__ Wl,
    const float* __restrict__ Wr, const float* __restrict__ bb,
    float* __restrict__ out, int rep) {
  __shared__ float sm[4][256];
  __shared__ float sx[4][256];
  const int w = threadIdx.x >> 6;
  const int f = threadIdx.x & 63;
  const int i = blockIdx.x * 4 + w;
  const int lo = rs[i];
  const int hi = rs[i + 1];

#pragma unroll 1
  for (int it = 0; it < rep; ++it) {
    float a0 = 0.f, a1 = 0.f, a2 = 0.f, a3 = 0.f;
    for (int e = lo; e < hi; ++e) {
      const float* p = h1 + (size_t)ss[e] * 256;
      a0 += p[f]; a1 += p[f + 64]; a2 += p[f + 128]; a3 += p[f + 192];
    }
    const float inv = 1.f / (float)max(hi - lo, 1);
    sm[w][f] = a0 * inv; sm[w][f + 64] = a1 * inv;
    sm[w][f + 128] = a2 * inv; sm[w][f + 192] = a3 * inv;
    const float* q = h1 + (size_t)i * 256;
    sx[w][f] = q[f]; sx[w][f + 64] = q[f + 64];
    sx[w][f + 128] = q[f + 128]; sx[w][f + 192] = q[f + 192];

    float acc = -1e30f;
    if (f < 47) {
      float a = bb[f];
      for (int k = 0; k < 256; ++k) {
        a += sm[w][k] * Wl[k * 47 + f] + sx[w][k] * Wr[k * 47 + f];
      }
      acc = a;
    }
    float m = acc;
#pragma unroll
    for (int off = 32; off; off >>= 1) m = fmaxf(m, __shfl_xor(m, off));
    float e2 = (f < 47) ? expf(acc - m) : 0.f;
    float s = e2;
#pragma unroll
    for (int off = 32; off; off >>= 1) s += __shfl_xor(s, off);
    if (f < 47) out[(size_t)i * 47 + f] = acc - m - logf(s);
  }
}

extern "C" void kernel_launch(void* const* d_in, const int* in_sizes, int n_in,
                              void* d_out, int out_size, void* d_ws, size_t ws_size,
                              hipStream_t stream) {
  const float* x    = (const float*)d_in[0];
  const int*   src0 = (const int*)d_in[1];
  const int*   dst0 = (const int*)d_in[2];
  const int*   src1 = (const int*)d_in[3];
  const int*   dst1 = (const int*)d_in[4];
  const int*   src2 = (const int*)d_in[5];
  const int*   dst2 = (const int*)d_in[6];
  const float* Wl0  = (const float*)d_in[7];
  const float* Wr0  = (const float*)d_in[8];
  const float* b0   = (const float*)d_in[9];
  const float* Wl1  = (const float*)d_in[10];
  const float* Wr1  = (const float*)d_in[11];
  const float* b1   = (const float*)d_in[12];
  const float* Wl2  = (const float*)d_in[13];
  const float* Wr2  = (const float*)d_in[14];
  const float* b2   = (const float*)d_in[15];
  float* out = (float*)d_out;

  const int N0 = 60000, N1 = 6000, N2 = 1024;

  char* base = (char*)d_ws;
  unsigned short* bm0  = (unsigned short*)(base);
  unsigned short* bm1  = (unsigned short*)(base + 114688);
  unsigned short* am0  = (unsigned short*)(base + 376832);
  unsigned short* h0b  = (unsigned short*)(base + 27271168);
  unsigned*       h0bu = (unsigned*)(base + 27271168);
  unsigned short* mean1= (unsigned short*)(base + 58007552);
  unsigned*       mean1u=(unsigned*)(base + 58007552);
  float* h1            = (float*)(base + 61087744);
  int* iw              = (int*)(base + 67248128);
  int* row0 = iw + ROW0_OFF;
  int* row1 = iw + ROW1_OFF;
  int* row2 = iw + ROW2_OFF;
  int* cnt  = iw + CNT_OFF;
  int* rank = iw + RANK_OFF;
  int* ss0  = iw + SS0_OFF;
  int* ss1  = iw + SS1_OFF;
  int* ss2  = iw + SS2_OFF;
  int* dummy= iw + DUMMY_OFF;

  // ---- 64 no-op dispatches: measure per-launch overhead ----
  for (int i = 0; i < 64; ++i) noop_k<<<1, 64, 0, stream>>>(dummy);

  // ---- CSR build ----
  hipMemsetAsync(cnt, 0, (size_t)67024 * sizeof(int), stream);
  histrank_k<<<HB, 256, 0, stream>>>(dst0, dst1, dst2, cnt, rank);
  scanpack_k<<<132 + 736, 256, 0, stream>>>(cnt, row0, row1, row2,
                                            Wl0, Wr0, bm0, Wl1, Wr1, bm1,
                                            /*rep=*/48);
  fillscatter_k<<<HB, 256, 0, stream>>>(dst0, dst1, dst2, src0, src1, src2,
                                        row0, row1, row2, rank, ss0, ss1, ss2,
                                        /*rep=*/40);

  // ---- Layer 0 ----
  gather_fused_k<<<(N0 * 64 + 255) / 256, 256, 0, stream>>>(x, ss0, row0, am0, N0);
  gemm0_k<<<(N0 + 63) / 64, 256, 0, stream>>>(am0, bm0, b0, h0b, N0, /*rep=*/16);

  // ---- Layer 1 ----
  gather_mean_b16_k<<<(N1 * 64 + 255) / 256, 256, 0, stream>>>(
      h0bu, ss1, row1, mean1u, N1, /*rep=*/24);
  gemm1_k<<<(N1 + 31) / 32, 256, 0, stream>>>(mean1, h0b, bm1, b1, h1, N1);

  // ---- Layer 2 ----
  final_fused_k<<<N2 / 4, 256, 0, stream>>>(h1, ss2, row2, Wl2, Wr2, b2, out,
                                            /*rep=*/64);
}

// Round 14
// 230.517 us; speedup vs baseline: 10.2314x; 10.2314x over previous
//
#include <hip/hip_runtime.h>
#include <hip/hip_bf16.h>

// GraphSAGE 3-layer. Round 14 = Round 12 +
//  (1) hierarchical scan: tilesum_pack (132 tile sums || weight pack) +
//      scanwrite (prefix over <=118 tsums)  [was scanpack: 15.7 us flat prefix]
//  (2) gather1: 2 waves per row (12K waves) for L2-latency hiding.
// Ledger @255.9: g0 88.6 | hist ~40 | gemm0 22 | scan 15.7 | g1 15 | gemm1 8 |
//                fill ~6 | final 5 | memset 2 | gaps ~18.

typedef short bf16x8 __attribute__((ext_vector_type(8)));
typedef float f32x4 __attribute__((ext_vector_type(4)));

static __device__ __forceinline__ unsigned short f2bf(float f) {
  unsigned u = __float_as_uint(f);
  unsigned r = u + 0x7FFFu + ((u >> 16) & 1u);  // RNE
  return (unsigned short)(r >> 16);
}
static __device__ __forceinline__ float bf2f_lo(unsigned u) {
  return __uint_as_float(u << 16);
}
static __device__ __forceinline__ float bf2f_hi(unsigned u) {
  return __uint_as_float(u & 0xFFFF0000u);
}
static __device__ __forceinline__ unsigned packbf(float lo, float hi) {
  return ((unsigned)f2bf(hi) << 16) | (unsigned)f2bf(lo);
}

// ---- sizes ----
#define E0C 900000
#define E1C 60000
#define E2C 5120
#define ETC 965120
#define HB  3770

// ---- int-workspace offsets ----
#define ROW0_OFF 0
#define ROW1_OFF 60001
#define ROW2_OFF 66002
#define CNT_OFF  67027
#define RANK_OFF 134051
#define SS0_OFF  1099171
#define SS1_OFF  1999171
#define SS2_OFF  2059171
#define TSUM_OFF 2064300

struct TileGeom { int tin, goff, n, tbeg, T; };
static __device__ __forceinline__ TileGeom tile_geom(int b) {
  TileGeom g;
  if (b < 118)      { g.tin = b;       g.goff = 0;     g.n = 60000; g.tbeg = 0;   g.T = 118; }
  else if (b < 130) { g.tin = b - 118; g.goff = 60000; g.n = 6000;  g.tbeg = 118; g.T = 12; }
  else              { g.tin = b - 130; g.goff = 66000; g.n = 1024;  g.tbeg = 130; g.T = 2; }
  return g;
}

// ---------- hist with rank capture ----------
__global__ __launch_bounds__(256) void histrank_k(
    const int* __restrict__ d0, const int* __restrict__ d1, const int* __restrict__ d2,
    int* __restrict__ cnt, int* __restrict__ rank) {
  int t = blockIdx.x * 256 + threadIdx.x;
  if (t < E0C) {
    rank[t] = atomicAdd(&cnt[d0[t]], 1);
  } else if (t < E0C + E1C) {
    rank[t] = atomicAdd(&cnt[60000 + d1[t - E0C]], 1);
  } else if (t < ETC) {
    rank[t] = atomicAdd(&cnt[66000 + d2[t - E0C - E1C]], 1);
  }
}

// ---------- tile sums (132 blocks) || weight packing (736 blocks) ----------
__global__ __launch_bounds__(256) void tilesum_pack_k(
    const int* __restrict__ cnt, int* __restrict__ tsum,
    const float* __restrict__ Wl0, const float* __restrict__ Wr0,
    unsigned short* __restrict__ bm0,
    const float* __restrict__ Wl1, const float* __restrict__ Wr1,
    unsigned short* __restrict__ bm1) {
  const int b = blockIdx.x;
  const int tid = threadIdx.x;
  if (b < 132) {
    __shared__ int red[256];
    const TileGeom g = tile_geom(b);
    const int i0 = g.tin * 512 + 2 * tid;
    int s = 0;
    if (i0 < g.n) s += cnt[g.goff + i0];
    if (i0 + 1 < g.n) s += cnt[g.goff + i0 + 1];
    red[tid] = s;
    __syncthreads();
    for (int off = 128; off; off >>= 1) {
      if (tid < off) red[tid] += red[tid + off];
      __syncthreads();
    }
    if (tid == 0) tsum[b] = red[0];
  } else {
    int j = b - 132;
    int n = tid;
    if (j < 224) {
      int k = j;
      float v = 0.f;
      if (k < 100) v = Wl0[(size_t)k * 256 + n];
      else if (k >= 112 && k < 212) v = Wr0[(size_t)(k - 112) * 256 + n];
      bm0[(((size_t)(k >> 3) * 256) + n) * 8 + (k & 7)] = f2bf(v);
    } else {
      int k = j - 224;
      float v = (k < 256) ? Wl1[(size_t)k * 256 + n] : Wr1[(size_t)(k - 256) * 256 + n];
      bm1[(((size_t)(k >> 3) * 256) + n) * 8 + (k & 7)] = f2bf(v);
    }
  }
}

// ---------- per-tile scan: prefix over tile sums + 512-elem local scan ----------
__global__ __launch_bounds__(256) void scanwrite_k(
    const int* __restrict__ cnt, const int* __restrict__ tsum,
    int* __restrict__ row0, int* __restrict__ row1, int* __restrict__ row2) {
  __shared__ int sc[256];
  const int b = blockIdx.x;
  const TileGeom g = tile_geom(b);
  const int tid = threadIdx.x;
  int* row = (b < 118) ? row0 : (b < 130 ? row1 : row2);

  int p = 0;
  for (int t = g.tbeg + tid; t < b; t += 256) p += tsum[t];
  sc[tid] = p;
  __syncthreads();
  for (int off = 128; off; off >>= 1) {
    if (tid < off) sc[tid] += sc[tid + off];
    __syncthreads();
  }
  const int pref = sc[0];
  __syncthreads();

  const int i0 = g.tin * 512 + 2 * tid;
  const int e0 = (i0 < g.n) ? cnt[g.goff + i0] : 0;
  const int e1 = (i0 + 1 < g.n) ? cnt[g.goff + i0 + 1] : 0;
  sc[tid] = e0 + e1;
  __syncthreads();
  for (int off = 1; off < 256; off <<= 1) {
    int v = (tid >= off) ? sc[tid - off] : 0;
    __syncthreads();
    sc[tid] += v;
    __syncthreads();
  }
  const int excl = sc[tid] - (e0 + e1);
  const int o0 = pref + excl;
  const int o1 = o0 + e0;
  if (i0 < g.n) row[i0] = o0;
  if (i0 + 1 < g.n) row[i0 + 1] = o1;
  if (g.tin == g.T - 1 && tid == 255) row[g.n] = pref + sc[255];
}

// ---------- atomic-free fill (rank-based) ----------
__global__ __launch_bounds__(256) void fillscatter_k(
    const int* __restrict__ d0, const int* __restrict__ d1, const int* __restrict__ d2,
    const int* __restrict__ s0, const int* __restrict__ s1, const int* __restrict__ s2,
    const int* __restrict__ row0, const int* __restrict__ row1,
    const int* __restrict__ row2, const int* __restrict__ rank,
    int* __restrict__ o0, int* __restrict__ o1, int* __restrict__ o2) {
  int t = blockIdx.x * 256 + threadIdx.x;
  if (t < E0C) {
    o0[row0[d0[t]] + rank[t]] = s0[t];
  } else if (t < E0C + E1C) {
    int e = t - E0C;
    o1[row1[d1[e]] + rank[t]] = s1[e];
  } else if (t < ETC) {
    int e = t - E0C - E1C;
    o2[row2[d2[e]] + rank[t]] = s2[e];
  }
}

// ---------- gather0: wave-per-row mean + self-row conversion, f32 in ----------
__global__ __launch_bounds__(256) void gather_fused_k(
    const float* __restrict__ x, const int* __restrict__ ss,
    const int* __restrict__ rs, unsigned short* __restrict__ am, int n) {
  int idx = blockIdx.x * 256 + threadIdx.x;
  int w = idx >> 6;
  int f = idx & 63;
  if (w >= n) return;
  const int lo = rs[w];
  const int hi = rs[w + 1];
  float acc0 = 0.f, acc1 = 0.f;
  const int k1 = f + 64;
  int e = lo;
  for (; e + 4 <= hi; e += 4) {
    const float* p0 = x + (size_t)ss[e] * 100;
    const float* p1 = x + (size_t)ss[e + 1] * 100;
    const float* p2 = x + (size_t)ss[e + 2] * 100;
    const float* p3 = x + (size_t)ss[e + 3] * 100;
    acc0 += (p0[f] + p1[f]) + (p2[f] + p3[f]);
    if (k1 < 100) acc1 += (p0[k1] + p1[k1]) + (p2[k1] + p3[k1]);
  }
  for (; e < hi; ++e) {
    const float* p0 = x + (size_t)ss[e] * 100;
    acc0 += p0[f];
    if (k1 < 100) acc1 += p0[k1];
  }
  const float inv = 1.f / (float)max(hi - lo, 1);
  unsigned short* arow = am + (size_t)w * 224;
  arow[f] = f2bf(acc0 * inv);
  if (k1 < 112) arow[k1] = (k1 < 100) ? f2bf(acc1 * inv) : (unsigned short)0;
  const float* xrow = x + (size_t)w * 100;
  arow[112 + f] = f2bf(xrow[f]);
  if (k1 < 112) arow[112 + k1] = (k1 < 100) ? f2bf(xrow[k1]) : (unsigned short)0;
}

// ---------- gather1: 2 waves/row, each owns a 64-uint half of the 128-uint row ----------
__global__ __launch_bounds__(256) void gather_mean_b16_k(
    const unsigned* __restrict__ xbu, const int* __restrict__ ss,
    const int* __restrict__ rs, unsigned* __restrict__ meanu, int n) {
  int idx = blockIdx.x * 256 + threadIdx.x;
  int wp = idx >> 6;          // wave-pair index: 2 per row
  int f = idx & 63;
  int w = wp >> 1;            // row
  int half = wp & 1;          // which 64-uint half
  if (w >= n) return;
  const int lo = rs[w];
  const int hi = rs[w + 1];
  const int off = half * 64 + f;
  float al = 0.f, ah = 0.f;
  int e = lo;
  for (; e + 4 <= hi; e += 4) {
    unsigned u0 = xbu[(size_t)ss[e] * 128 + off];
    unsigned u1 = xbu[(size_t)ss[e + 1] * 128 + off];
    unsigned u2 = xbu[(size_t)ss[e + 2] * 128 + off];
    unsigned u3 = xbu[(size_t)ss[e + 3] * 128 + off];
    al += (bf2f_lo(u0) + bf2f_lo(u1)) + (bf2f_lo(u2) + bf2f_lo(u3));
    ah += (bf2f_hi(u0) + bf2f_hi(u1)) + (bf2f_hi(u2) + bf2f_hi(u3));
  }
  for (; e < hi; ++e) {
    unsigned u0 = xbu[(size_t)ss[e] * 128 + off];
    al += bf2f_lo(u0);
    ah += bf2f_hi(u0);
  }
  const float inv = 1.f / (float)max(hi - lo, 1);
  meanu[(size_t)w * 128 + off] = packbf(al * inv, ah * inv);
}

// ---------- gemm0: K=224, MBLK=64, LDS-coalesced bf16 epilogue ----------
__global__ __launch_bounds__(256) void gemm0_k(
    const unsigned short* __restrict__ A, const unsigned short* __restrict__ Bp,
    const float* __restrict__ bias, unsigned short* __restrict__ h0b, int M) {
  constexpr int LDA = 232;
  constexpr int LDC = 264;
  __shared__ unsigned short Sh[64 * LDC];

  const int row0 = blockIdx.x * 64;
  for (int t = threadIdx.x; t < 64 * 28; t += 256) {
    int r = t / 28;
    int c = t - r * 28;
    *reinterpret_cast<uint4*>(&Sh[r * LDA + c * 8]) =
        *reinterpret_cast<const uint4*>(A + (size_t)(row0 + r) * 224 + c * 8);
  }
  __syncthreads();

  const int wid = threadIdx.x >> 6;
  const int l = threadIdx.x & 63;
  const int l15 = l & 15;
  const int lhi = l >> 4;

  f32x4 acc[4][4];
#pragma unroll
  for (int rt = 0; rt < 4; ++rt)
#pragma unroll
    for (int ct = 0; ct < 4; ++ct) acc[rt][ct] = (f32x4){0.f, 0.f, 0.f, 0.f};

  for (int kc = 0; kc < 7; ++kc) {
    bf16x8 a[4], b[4];
#pragma unroll
    for (int rt = 0; rt < 4; ++rt)
      a[rt] = *reinterpret_cast<const bf16x8*>(
          &Sh[(rt * 16 + l15) * LDA + kc * 32 + lhi * 8]);
#pragma unroll
    for (int ct = 0; ct < 4; ++ct) {
      int n = wid * 64 + ct * 16 + l15;
      b[ct] = *reinterpret_cast<const bf16x8*>(
          Bp + ((size_t)(kc * 4 + lhi) * 256 + n) * 8);
    }
#pragma unroll
    for (int rt = 0; rt < 4; ++rt)
#pragma unroll
      for (int ct = 0; ct < 4; ++ct)
        acc[rt][ct] = __builtin_amdgcn_mfma_f32_16x16x32_bf16(a[rt], b[ct],
                                                              acc[rt][ct], 0, 0, 0);
  }
  __syncthreads();

#pragma unroll
  for (int rt = 0; rt < 4; ++rt) {
#pragma unroll
    for (int ct = 0; ct < 4; ++ct) {
      int col = wid * 64 + ct * 16 + l15;
      float bv = bias[col];
#pragma unroll
      for (int r = 0; r < 4; ++r) {
        int rr = rt * 16 + lhi * 4 + r;
        Sh[rr * LDC + col] = f2bf(fmaxf(acc[rt][ct][r] + bv, 0.f));
      }
    }
  }
  __syncthreads();

  const int mrem = M - row0;
  for (int t = threadIdx.x; t < 64 * 32; t += 256) {
    int r = t >> 5;
    int c = t & 31;
    if (r < mrem) {
      *reinterpret_cast<uint4*>(h0b + (size_t)(row0 + r) * 256 + c * 8) =
          *reinterpret_cast<const uint4*>(&Sh[r * LDC + c * 8]);
    }
  }
}

// ---------- gemm1: K=512 two-pointer A, f32 out ----------
__global__ __launch_bounds__(256) void gemm1_k(
    const unsigned short* __restrict__ A1, const unsigned short* __restrict__ A2,
    const unsigned short* __restrict__ Bp, const float* __restrict__ bias,
    float* __restrict__ h1, int M) {
  constexpr int LDA = 520;
  __shared__ unsigned short As[32 * LDA];

  const int row0 = blockIdx.x * 32;
  for (int t = threadIdx.x; t < 32 * 64; t += 256) {
    int r = t >> 6;
    int c = t & 63;
    const unsigned short* src = (c < 32)
        ? (A1 + (size_t)(row0 + r) * 256 + c * 8)
        : (A2 + (size_t)(row0 + r) * 256 + (c - 32) * 8);
    *reinterpret_cast<uint4*>(&As[r * LDA + c * 8]) =
        *reinterpret_cast<const uint4*>(src);
  }
  __syncthreads();

  const int wid = threadIdx.x >> 6;
  const int l = threadIdx.x & 63;
  const int l15 = l & 15;
  const int lhi = l >> 4;

  f32x4 acc[2][4];
#pragma unroll
  for (int rt = 0; rt < 2; ++rt)
#pragma unroll
    for (int ct = 0; ct < 4; ++ct) acc[rt][ct] = (f32x4){0.f, 0.f, 0.f, 0.f};

  for (int kc = 0; kc < 16; ++kc) {
    bf16x8 a[2], b[4];
#pragma unroll
    for (int rt = 0; rt < 2; ++rt)
      a[rt] = *reinterpret_cast<const bf16x8*>(
          &As[(rt * 16 + l15) * LDA + kc * 32 + lhi * 8]);
#pragma unroll
    for (int ct = 0; ct < 4; ++ct) {
      int n = wid * 64 + ct * 16 + l15;
      b[ct] = *reinterpret_cast<const bf16x8*>(
          Bp + ((size_t)(kc * 4 + lhi) * 256 + n) * 8);
    }
#pragma unroll
    for (int rt = 0; rt < 2; ++rt)
#pragma unroll
      for (int ct = 0; ct < 4; ++ct)
        acc[rt][ct] = __builtin_amdgcn_mfma_f32_16x16x32_bf16(a[rt], b[ct],
                                                              acc[rt][ct], 0, 0, 0);
  }

#pragma unroll
  for (int rt = 0; rt < 2; ++rt) {
#pragma unroll
    for (int ct = 0; ct < 4; ++ct) {
      int col = wid * 64 + ct * 16 + l15;
      float bv = bias[col];
#pragma unroll
      for (int r = 0; r < 4; ++r) {
        int row = row0 + rt * 16 + lhi * 4 + r;
        if (row < M)
          h1[(size_t)row * 256 + col] = fmaxf(acc[rt][ct][r] + bv, 0.f);
      }
    }
  }
}

// ---------- final: 4 waves/block, wave per row; gather2+GEMM+log_softmax ----------
__global__ __launch_bounds__(256) void final_fused_k(
    const float* __restrict__ h1, const int* __restrict__ ss,
    const int* __restrict__ rs, const float* __restrict__ Wl,
    const float* __restrict__ Wr, const float* __restrict__ bb,
    float* __restrict__ out) {
  __shared__ float sm[4][256];
  __shared__ float sx[4][256];
  const int w = threadIdx.x >> 6;
  const int f = threadIdx.x & 63;
  const int i = blockIdx.x * 4 + w;

  const int lo = rs[i];
  const int hi = rs[i + 1];
  float a0 = 0.f, a1 = 0.f, a2 = 0.f, a3 = 0.f;
  for (int e = lo; e < hi; ++e) {
    const float* p = h1 + (size_t)ss[e] * 256;
    a0 += p[f]; a1 += p[f + 64]; a2 += p[f + 128]; a3 += p[f + 192];
  }
  const float inv = 1.f / (float)max(hi - lo, 1);
  sm[w][f] = a0 * inv; sm[w][f + 64] = a1 * inv;
  sm[w][f + 128] = a2 * inv; sm[w][f + 192] = a3 * inv;
  const float* q = h1 + (size_t)i * 256;
  sx[w][f] = q[f]; sx[w][f + 64] = q[f + 64];
  sx[w][f + 128] = q[f + 128]; sx[w][f + 192] = q[f + 192];

  float acc = -1e30f;
  if (f < 47) {
    float a = bb[f];
    for (int k = 0; k < 256; ++k) {
      a += sm[w][k] * Wl[k * 47 + f] + sx[w][k] * Wr[k * 47 + f];
    }
    acc = a;
  }
  float m = acc;
#pragma unroll
  for (int off = 32; off; off >>= 1) m = fmaxf(m, __shfl_xor(m, off));
  float e2 = (f < 47) ? expf(acc - m) : 0.f;
  float s = e2;
#pragma unroll
  for (int off = 32; off; off >>= 1) s += __shfl_xor(s, off);
  if (f < 47) out[(size_t)i * 47 + f] = acc - m - logf(s);
}

extern "C" void kernel_launch(void* const* d_in, const int* in_sizes, int n_in,
                              void* d_out, int out_size, void* d_ws, size_t ws_size,
                              hipStream_t stream) {
  const float* x    = (const float*)d_in[0];
  const int*   src0 = (const int*)d_in[1];
  const int*   dst0 = (const int*)d_in[2];
  const int*   src1 = (const int*)d_in[3];
  const int*   dst1 = (const int*)d_in[4];
  const int*   src2 = (const int*)d_in[5];
  const int*   dst2 = (const int*)d_in[6];
  const float* Wl0  = (const float*)d_in[7];
  const float* Wr0  = (const float*)d_in[8];
  const float* b0   = (const float*)d_in[9];
  const float* Wl1  = (const float*)d_in[10];
  const float* Wr1  = (const float*)d_in[11];
  const float* b1   = (const float*)d_in[12];
  const float* Wl2  = (const float*)d_in[13];
  const float* Wr2  = (const float*)d_in[14];
  const float* b2   = (const float*)d_in[15];
  float* out = (float*)d_out;

  const int N0 = 60000, N1 = 6000, N2 = 1024;

  char* base = (char*)d_ws;
  unsigned short* bm0  = (unsigned short*)(base);
  unsigned short* bm1  = (unsigned short*)(base + 114688);
  unsigned short* am0  = (unsigned short*)(base + 376832);
  unsigned short* h0b  = (unsigned short*)(base + 27271168);
  unsigned*       h0bu = (unsigned*)(base + 27271168);
  unsigned short* mean1= (unsigned short*)(base + 58007552);
  unsigned*       mean1u=(unsigned*)(base + 58007552);
  float* h1            = (float*)(base + 61087744);
  int* iw              = (int*)(base + 67248128);
  int* row0 = iw + ROW0_OFF;
  int* row1 = iw + ROW1_OFF;
  int* row2 = iw + ROW2_OFF;
  int* cnt  = iw + CNT_OFF;
  int* rank = iw + RANK_OFF;
  int* ss0  = iw + SS0_OFF;
  int* ss1  = iw + SS1_OFF;
  int* ss2  = iw + SS2_OFF;
  int* tsum = iw + TSUM_OFF;

  // ---- CSR build ----
  hipMemsetAsync(cnt, 0, (size_t)67024 * sizeof(int), stream);
  histrank_k<<<HB, 256, 0, stream>>>(dst0, dst1, dst2, cnt, rank);
  tilesum_pack_k<<<132 + 736, 256, 0, stream>>>(cnt, tsum, Wl0, Wr0, bm0,
                                                Wl1, Wr1, bm1);
  scanwrite_k<<<132, 256, 0, stream>>>(cnt, tsum, row0, row1, row2);
  fillscatter_k<<<HB, 256, 0, stream>>>(dst0, dst1, dst2, src0, src1, src2,
                                        row0, row1, row2, rank, ss0, ss1, ss2);

  // ---- Layer 0 ----
  gather_fused_k<<<(N0 * 64 + 255) / 256, 256, 0, stream>>>(x, ss0, row0, am0, N0);
  gemm0_k<<<(N0 + 63) / 64, 256, 0, stream>>>(am0, bm0, b0, h0b, N0);

  // ---- Layer 1 (2 waves/row gather) ----
  gather_mean_b16_k<<<(N1 * 2 * 64 + 255) / 256, 256, 0, stream>>>(
      h0bu, ss1, row1, mean1u, N1);
  gemm1_k<<<(N1 + 31) / 32, 256, 0, stream>>>(mean1, h0b, bm1, b1, h1, N1);

  // ---- Layer 2 (fused final, wave-per-row) ----
  final_fused_k<<<N2 / 4, 256, 0, stream>>>(h1, ss2, row2, Wl2, Wr2, b2, out);
}